// Round 1
// baseline (2172.868 us; speedup 1.0000x reference)
//
#include <hip/hip_runtime.h>
#include <stdint.h>

// Problem constants
constexpr int BB = 64;     // batch
constexpr int SS = 512;    // seq len
constexpr int DD = 256;    // emb dim
constexpr int HH = 256;    // hidden
constexpr int NHH = 4;     // heads
constexpr int KK = 1024;   // NH*H recurrent input dim
constexpr int NJ4 = 32;    // per-thread uint4 count (8 f16 each) over its 256-input chunk
constexpr int WLDS_J4 = 3; // how many 16KB j4-blocks of Wpack staged in LDS (48KB)

typedef _Float16 f16;
typedef _Float16 f16x2 __attribute__((ext_vector_type(2)));

__device__ inline float dot2p(uint32_t a, uint32_t b, float c) {
  f16x2 av = __builtin_bit_cast(f16x2, a);
  f16x2 bv = __builtin_bit_cast(f16x2, b);
#if defined(__has_builtin)
#if __has_builtin(__builtin_amdgcn_fdot2)
  return __builtin_amdgcn_fdot2(av, bv, c, false);
#else
  return c + (float)av.x * (float)bv.x + (float)av.y * (float)bv.y;
#endif
#else
  return c + (float)av.x * (float)bv.x + (float)av.y * (float)bv.y;
#endif
}

__device__ inline uint32_t pack2(float a, float b) {
  f16x2 v;
  v.x = (f16)a;
  v.y = (f16)b;
  return __builtin_bit_cast(uint32_t, v);
}

__device__ inline float fast_tanh(float x) {
  x = fminf(fmaxf(x, -15.f), 15.f);
  float e = __expf(2.f * x);
  return 1.f - 2.f / (e + 1.f);
}

// ---------------------------------------------------------------------------
// Prep A1: pack Wh [H, K] fp32 -> Wpack f16, layout Wpack[j4*1024 + tid],
// tid = q*256 + o, holding Wh[o, 256q + 8*j4 .. +8) as 8 packed f16.
// Inner-loop global reads of Wpack are then perfectly coalesced (16KB / j4).
// ---------------------------------------------------------------------------
__global__ void k_pack_wh(const float* __restrict__ Wh, uint4* __restrict__ Wpack) {
  int g = blockIdx.x * blockDim.x + threadIdx.x; // 32768
  int j4 = g >> 10, tid = g & 1023;
  int o = tid & 255, q = tid >> 8;
  const float* s = Wh + o * KK + q * 256 + j4 * 8;
  uint4 w;
  w.x = pack2(s[0], s[1]);
  w.y = pack2(s[2], s[3]);
  w.z = pack2(s[4], s[5]);
  w.w = pack2(s[6], s[7]);
  Wpack[g] = w;
}

// ---------------------------------------------------------------------------
// Prep A2/A3: transpose src[r, C] (r in [0,256)) -> dst[c*256 + r]
// Coalesced writes; reads hit L1/L2 line-reuse across the c walk.
// ---------------------------------------------------------------------------
__global__ void k_transpose8(const float* __restrict__ src, float* __restrict__ dst,
                             int C, int total) {
  int g = blockIdx.x * blockDim.x + threadIdx.x;
  if (g >= total) return;
  int r = g & 255, c = g >> 8;
  dst[g] = src[r * C + c];
}

// ---------------------------------------------------------------------------
// Prep B: U[row, o] = emb[src[row]] @ Wi^T + bi + bh   (f16 out)
// rows = b*512 + t. 32 rows per WG of 256 threads; x staged fp32 in LDS.
// Thread (g8, c): rows 4*g8..+4, cols 8c..+8 -> 32 accumulators.
// ---------------------------------------------------------------------------
__global__ __launch_bounds__(256) void k_precompute_u(
    const int* __restrict__ src, const float* __restrict__ emb,
    const float* __restrict__ WiT, const float* __restrict__ bi,
    const float* __restrict__ bh, f16* __restrict__ U) {
  __shared__ float xs[32 * 256];
  __shared__ int srcs[32];
  const int tid = threadIdx.x;
  const int row0 = blockIdx.x * 32;
  if (tid < 32) srcs[tid] = src[row0 + tid];
  __syncthreads();
  for (int i = tid; i < 32 * 256; i += 256) {
    int r = i >> 8, d = i & 255;
    xs[i] = emb[srcs[r] * DD + d];
  }
  __syncthreads();
  const int g8 = tid >> 5, c = tid & 31;
  float acc[4][8];
#pragma unroll
  for (int r = 0; r < 4; ++r)
#pragma unroll
    for (int j = 0; j < 8; ++j) acc[r][j] = 0.f;

  for (int d = 0; d < 256; ++d) {
    float4 w0 = *(const float4*)(WiT + d * 256 + c * 8);
    float4 w1 = *(const float4*)(WiT + d * 256 + c * 8 + 4);
#pragma unroll
    for (int r = 0; r < 4; ++r) {
      float x = xs[(g8 * 4 + r) * 256 + d];
      acc[r][0] += x * w0.x;
      acc[r][1] += x * w0.y;
      acc[r][2] += x * w0.z;
      acc[r][3] += x * w0.w;
      acc[r][4] += x * w1.x;
      acc[r][5] += x * w1.y;
      acc[r][6] += x * w1.z;
      acc[r][7] += x * w1.w;
    }
  }
#pragma unroll
  for (int r = 0; r < 4; ++r) {
    int row = row0 + g8 * 4 + r;
    f16* dst = U + (size_t)row * HH + c * 8;
#pragma unroll
    for (int j = 0; j < 8; ++j)
      dst[j] = (f16)(acc[r][j] + bi[c * 8 + j] + bh[c * 8 + j]);
  }
}

// ---------------------------------------------------------------------------
// Main recurrence: one WG (1024 threads) per batch element.
// Thread (o, q): output o, K-chunk [256q, 256q+256). Per step:
//   phase1: partial = sum over chunk via v_dot2 (weights streamed L2/LDS,
//           activations = wave-uniform ds_read_b128 broadcast)
//   phase2: threads o<256 reduce 4 partials + U, tanh, gate-EMA the 4 heads
//           (fp32 master h in LDS), requantize hcat to f16.
// Loops only input_len[b] steps; epilogue does fc1(tanh)+fc2 in-WG.
// ---------------------------------------------------------------------------
__global__ __launch_bounds__(1024) void k_recurrence(
    const uint4* __restrict__ Wpack, const f16* __restrict__ U,
    const float* __restrict__ fix_src, const int* __restrict__ input_len,
    const float* __restrict__ fc1T, const float* __restrict__ fc1_b,
    const float* __restrict__ fc2_W, const float* __restrict__ fc2_b,
    float* __restrict__ out) {
  __shared__ uint4 wlds[WLDS_J4 * 1024];  // 48KB staged weights (j4 = 0..2)
  __shared__ uint4 hcatv[KK / 8];         // 2KB f16 activations
  __shared__ float hstate[NHH * HH];      // 4KB fp32 master h
  __shared__ float partials[1024];        // 4KB
  __shared__ float hidb[HH];              // 1KB
  f16* hcat_h = (f16*)hcatv;

  const int b = blockIdx.x;
  const int tid = threadIdx.x;
  const int o = tid & 255, q = tid >> 8;

  for (int i = tid; i < WLDS_J4 * 1024; i += 1024) wlds[i] = Wpack[i];
  hstate[tid] = 0.f;
  if (tid < KK / 8) hcatv[tid] = make_uint4(0u, 0u, 0u, 0u);
  __syncthreads();

  const int len = input_len[b];
  const f16* Ub = U + (size_t)b * SS * HH;
  const float* fsb = fix_src + b * SS;

  for (int t = 0; t < len; ++t) {
    float uval = 0.f, dval = 0.f;
    if (tid < 256) {  // prefetch early so latency hides under the matvec
      uval = (float)Ub[t * HH + o];
      dval = fsb[t];
    }
    float acc = 0.f;
    const uint4* actp = hcatv + q * NJ4;
#pragma unroll
    for (int j4 = 0; j4 < WLDS_J4; ++j4) {
      uint4 w = wlds[j4 * 1024 + tid];
      uint4 a = actp[j4];
      acc = dot2p(w.x, a.x, acc);
      acc = dot2p(w.y, a.y, acc);
      acc = dot2p(w.z, a.z, acc);
      acc = dot2p(w.w, a.w, acc);
    }
#pragma unroll 4
    for (int j4 = WLDS_J4; j4 < NJ4; ++j4) {
      uint4 w = Wpack[j4 * 1024 + tid];
      uint4 a = actp[j4];
      acc = dot2p(w.x, a.x, acc);
      acc = dot2p(w.y, a.y, acc);
      acc = dot2p(w.z, a.z, acc);
      acc = dot2p(w.w, a.w, acc);
    }
    partials[tid] = acc;
    __syncthreads();
    if (tid < 256) {
      float pre = partials[o] + partials[256 + o] + partials[512 + o] +
                  partials[768 + o] + uval;
      float c = fast_tanh(pre);
#pragma unroll
      for (int n = 0; n < NHH; ++n) {
        float g = 1.f / (1.f + __expf((float)(3 * n) - dval));
        float hn = hstate[n * HH + o];
        hn = g * c + (1.f - g) * hn;
        hstate[n * HH + o] = hn;
        hcat_h[n * HH + o] = (f16)hn;
      }
    }
    __syncthreads();
  }

  // ---- epilogue: hid = tanh(sel @ fc1_W^T + fc1_b); out = hid @ fc2_W^T + fc2_b
  {
    float acc = 0.f;
    const int base = q * 256;
    for (int i = 0; i < 256; ++i) {
      acc += hstate[base + i] * fc1T[(size_t)(base + i) * HH + o];
    }
    partials[tid] = acc;
  }
  __syncthreads();
  if (tid < 256) {
    float pre = partials[o] + partials[256 + o] + partials[512 + o] +
                partials[768 + o] + fc1_b[o];
    hidb[o] = fast_tanh(pre);
  }
  __syncthreads();
  if (tid < 64) {
    float p0 = 0.f, p1 = 0.f;
    for (int oo = tid; oo < 256; oo += 64) {
      float h = hidb[oo];
      p0 += h * fc2_W[oo];
      p1 += h * fc2_W[256 + oo];
    }
#pragma unroll
    for (int off = 32; off; off >>= 1) {
      p0 += __shfl_down(p0, off);
      p1 += __shfl_down(p1, off);
    }
    if (tid == 0) {
      out[b * 2 + 0] = p0 + fc2_b[0];
      out[b * 2 + 1] = p1 + fc2_b[1];
    }
  }
}

// ---------------------------------------------------------------------------
// Host launcher
// ws layout: [0,512K) Wpack | [512K,768K) WiT | [768K,1792K) fc1T | [1792K, +16M) U
// ---------------------------------------------------------------------------
extern "C" void kernel_launch(void* const* d_in, const int* in_sizes, int n_in,
                              void* d_out, int out_size, void* d_ws, size_t ws_size,
                              hipStream_t stream) {
  const int* src = (const int*)d_in[0];
  const int* input_len = (const int*)d_in[1];
  const float* fix_src = (const float*)d_in[2];
  const float* emb = (const float*)d_in[3];
  const float* Wi = (const float*)d_in[4];
  const float* bi = (const float*)d_in[5];
  const float* Wh = (const float*)d_in[6];
  const float* bh = (const float*)d_in[7];
  const float* fc1_W = (const float*)d_in[8];
  const float* fc1_b = (const float*)d_in[9];
  const float* fc2_W = (const float*)d_in[10];
  const float* fc2_b = (const float*)d_in[11];
  float* out = (float*)d_out;

  char* ws = (char*)d_ws;
  uint4* Wpack = (uint4*)(ws);                        // 512 KB
  float* WiT = (float*)(ws + (512ull << 10));         // 256 KB
  float* fc1T = (float*)(ws + (768ull << 10));        // 1 MB
  f16* U = (f16*)(ws + (1792ull << 10));              // 16 MB
  const size_t needed = (1792ull << 10) + (size_t)BB * SS * HH * sizeof(f16);
  if (ws_size < needed) return;  // not enough scratch; bail (will show as absmax fail)

  k_pack_wh<<<128, 256, 0, stream>>>(Wh, Wpack);
  k_transpose8<<<(65536 + 255) / 256, 256, 0, stream>>>(Wi, WiT, 256, 65536);
  k_transpose8<<<(262144 + 255) / 256, 256, 0, stream>>>(fc1_W, fc1T, 1024, 262144);
  k_precompute_u<<<BB * SS / 32, 256, 0, stream>>>(src, emb, WiT, bi, bh, U);
  k_recurrence<<<BB, 1024, 0, stream>>>(Wpack, U, fix_src, input_len, fc1T, fc1_b,
                                        fc2_W, fc2_b, out);
}

// Round 2
// 1223.808 us; speedup vs baseline: 1.7755x; 1.7755x over previous
//
#include <hip/hip_runtime.h>
#include <stdint.h>

// Problem constants
constexpr int BB = 64;     // batch
constexpr int SS = 512;    // seq len
constexpr int DD = 256;    // emb dim
constexpr int HH = 256;    // hidden
constexpr int NHH = 4;     // heads
constexpr int KK = 1024;   // NH*H recurrent input dim

// Recurrence kernel geometry: 512 threads, thread (p, oo) covers outputs
// {oo, oo+128} over input chunk [256p, 256p+256). Per-thread weights:
// 64 uint4 (8 f16 each). Storage: 52 slots VGPR + 6 slots LDS + 6 slots
// VGPR (hoisted "G" region) = all weights CU-resident, zero per-step L2.
constexpr int TT = 512;   // recurrence WG size
constexpr int NV = 52;    // V-region uint4 slots per thread (208 VGPRs)
constexpr int NL = 6;     // LDS-region slots (6 * 512 * 16B = 48 KB)
constexpr int NG = 6;     // hoisted G-region slots (24 VGPRs)

typedef _Float16 f16;
typedef _Float16 f16x2 __attribute__((ext_vector_type(2)));

__device__ inline float dot2p(uint32_t a, uint32_t b, float c) {
  f16x2 av = __builtin_bit_cast(f16x2, a);
  f16x2 bv = __builtin_bit_cast(f16x2, b);
#if defined(__has_builtin)
#if __has_builtin(__builtin_amdgcn_fdot2)
  return __builtin_amdgcn_fdot2(av, bv, c, false);
#else
  return c + (float)av.x * (float)bv.x + (float)av.y * (float)bv.y;
#endif
#else
  return c + (float)av.x * (float)bv.x + (float)av.y * (float)bv.y;
#endif
}

__device__ inline float dot8(uint4 w, uint4 a, float c) {
  c = dot2p(w.x, a.x, c);
  c = dot2p(w.y, a.y, c);
  c = dot2p(w.z, a.z, c);
  c = dot2p(w.w, a.w, c);
  return c;
}

__device__ inline uint32_t pack2(float a, float b) {
  f16x2 v;
  v.x = (f16)a;
  v.y = (f16)b;
  return __builtin_bit_cast(uint32_t, v);
}

__device__ inline float fast_tanh(float x) {
  x = fminf(fmaxf(x, -15.f), 15.f);
  float e = __expf(2.f * x);
  return 1.f - 2.f / (e + 1.f);
}

// ---------------------------------------------------------------------------
// Prep A1: pack Wh [256, 1024] fp32 -> Wpack f16 in slot layout
// Wpack[m*512 + tid], tid = p*128 + oo. Slot m -> (out_sel, j):
//   m in [0,52):  os = m&1,      j = m>>1          (VGPR region)
//   m in [52,58): os = (m-52)&1, j = 26 + (m-52)>>1 (LDS region)
//   m in [58,64): os = (m-58)&1, j = 29 + (m-58)>>1 (hoisted G region)
// holds Wh[oo + 128*os, 256p + 8j .. +8) as 8 packed f16.
// ---------------------------------------------------------------------------
__global__ void k_pack_wh(const float* __restrict__ Wh, uint4* __restrict__ Wpack) {
  int g = blockIdx.x * blockDim.x + threadIdx.x;  // 32768
  int m = g >> 9, tid = g & 511;
  int oo = tid & 127, p = tid >> 7;
  int os, j;
  if (m < 52) {
    os = m & 1;
    j = m >> 1;
  } else if (m < 58) {
    os = (m - 52) & 1;
    j = 26 + ((m - 52) >> 1);
  } else {
    os = (m - 58) & 1;
    j = 29 + ((m - 58) >> 1);
  }
  int row = oo + (os << 7);
  int col = (p << 8) + (j << 3);
  const float* s = Wh + row * KK + col;
  uint4 w;
  w.x = pack2(s[0], s[1]);
  w.y = pack2(s[2], s[3]);
  w.z = pack2(s[4], s[5]);
  w.w = pack2(s[6], s[7]);
  Wpack[g] = w;
}

// ---------------------------------------------------------------------------
// Prep A2/A3: transpose src[r, C] (r in [0,256)) -> dst[c*256 + r]
// ---------------------------------------------------------------------------
__global__ void k_transpose8(const float* __restrict__ src, float* __restrict__ dst,
                             int C, int total) {
  int g = blockIdx.x * blockDim.x + threadIdx.x;
  if (g >= total) return;
  int r = g & 255, c = g >> 8;
  dst[g] = src[r * C + c];
}

// ---------------------------------------------------------------------------
// Prep B: U[row, o] = emb[src[row]] @ Wi^T + bi + bh   (f16 out)
// ---------------------------------------------------------------------------
__global__ __launch_bounds__(256) void k_precompute_u(
    const int* __restrict__ src, const float* __restrict__ emb,
    const float* __restrict__ WiT, const float* __restrict__ bi,
    const float* __restrict__ bh, f16* __restrict__ U) {
  __shared__ float xs[32 * 256];
  __shared__ int srcs[32];
  const int tid = threadIdx.x;
  const int row0 = blockIdx.x * 32;
  if (tid < 32) srcs[tid] = src[row0 + tid];
  __syncthreads();
  for (int i = tid; i < 32 * 256; i += 256) {
    int r = i >> 8, d = i & 255;
    xs[i] = emb[srcs[r] * DD + d];
  }
  __syncthreads();
  const int g8 = tid >> 5, c = tid & 31;
  float acc[4][8];
#pragma unroll
  for (int r = 0; r < 4; ++r)
#pragma unroll
    for (int j = 0; j < 8; ++j) acc[r][j] = 0.f;

  for (int d = 0; d < 256; ++d) {
    float4 w0 = *(const float4*)(WiT + d * 256 + c * 8);
    float4 w1 = *(const float4*)(WiT + d * 256 + c * 8 + 4);
#pragma unroll
    for (int r = 0; r < 4; ++r) {
      float x = xs[(g8 * 4 + r) * 256 + d];
      acc[r][0] += x * w0.x;
      acc[r][1] += x * w0.y;
      acc[r][2] += x * w0.z;
      acc[r][3] += x * w0.w;
      acc[r][4] += x * w1.x;
      acc[r][5] += x * w1.y;
      acc[r][6] += x * w1.z;
      acc[r][7] += x * w1.w;
    }
  }
#pragma unroll
  for (int r = 0; r < 4; ++r) {
    int row = row0 + g8 * 4 + r;
    f16* dst = U + (size_t)row * HH + c * 8;
#pragma unroll
    for (int j = 0; j < 8; ++j)
      dst[j] = (f16)(acc[r][j] + bi[c * 8 + j] + bh[c * 8 + j]);
  }
}

// ---------------------------------------------------------------------------
// Main recurrence: one WG (512 threads = 8 waves) per batch element.
// All Wh weights CU-resident: 58 uint4/thread in VGPRs + 6 in LDS.
// __launch_bounds__(512,2): 2 waves/EU -> 256-VGPR budget per thread.
// ---------------------------------------------------------------------------
__global__ __launch_bounds__(512, 2) void k_recurrence(
    const uint4* __restrict__ Wpack, const f16* __restrict__ U,
    const float* __restrict__ fix_src, const int* __restrict__ input_len,
    const float* __restrict__ fc1T, const float* __restrict__ fc1_b,
    const float* __restrict__ fc2_W, const float* __restrict__ fc2_b,
    float* __restrict__ out) {
  __shared__ uint4 wlds[NL * TT];     // 48 KB weights
  __shared__ uint4 hcatv[KK / 8];     // 2 KB f16 activations
  __shared__ float hstate[NHH * HH];  // 4 KB fp32 master h
  __shared__ float partials[1024];    // 4 KB
  __shared__ float hidb[HH];          // 1 KB
  f16* hcat_h = (f16*)hcatv;

  const int b = blockIdx.x;
  const int tid = threadIdx.x;
  const int oo = tid & 127, p = tid >> 7;  // outputs {oo, oo+128}, K-chunk p
  const int o = tid & 255;                 // phase2 / epilogue index

  // ---- one-time: weights into VGPRs + LDS
  uint4 wv[NV];
#pragma unroll
  for (int m = 0; m < NV; ++m) wv[m] = Wpack[m * TT + tid];
  uint4 gg[NG];
#pragma unroll
  for (int i = 0; i < NG; ++i) gg[i] = Wpack[(NV + NL + i) * TT + tid];
#pragma unroll
  for (int i = 0; i < NL; ++i) wlds[i * TT + tid] = Wpack[(NV + i) * TT + tid];
  hstate[tid] = 0.f;
  hstate[512 + tid] = 0.f;
  if (tid < KK / 8) hcatv[tid] = make_uint4(0u, 0u, 0u, 0u);
  __syncthreads();

  const int len = input_len[b];
  const f16* Ub = U + (size_t)b * SS * HH;
  const float* fsb = fix_src + b * SS;
  const uint4* actp = hcatv + p * 32;  // wave-uniform base -> broadcast reads

#pragma unroll 1
  for (int t = 0; t < len; ++t) {
    float uval = 0.f, dval = 0.f;
    if (tid < 256) {  // prefetch; hides under the matvec
      uval = (float)Ub[t * HH + o];
      dval = fsb[t];
    }
    float a0 = 0.f, a1 = 0.f;
#pragma unroll
    for (int j = 0; j < 26; ++j) {
      uint4 a = actp[j];
      a0 = dot8(wv[2 * j], a, a0);
      a1 = dot8(wv[2 * j + 1], a, a1);
    }
#pragma unroll
    for (int j = 26; j < 29; ++j) {
      uint4 a = actp[j];
      int i = j - 26;
      a0 = dot8(wlds[(2 * i) * TT + tid], a, a0);
      a1 = dot8(wlds[(2 * i + 1) * TT + tid], a, a1);
    }
#pragma unroll
    for (int j = 29; j < 32; ++j) {
      uint4 a = actp[j];
      int i = j - 29;
      a0 = dot8(gg[2 * i], a, a0);
      a1 = dot8(gg[2 * i + 1], a, a1);
    }
    partials[p * 256 + oo] = a0;
    partials[p * 256 + 128 + oo] = a1;
    __syncthreads();
    if (tid < 256) {
      float pre = partials[o] + partials[256 + o] + partials[512 + o] +
                  partials[768 + o] + uval;
      float c = fast_tanh(pre);
#pragma unroll
      for (int n = 0; n < NHH; ++n) {
        float g = 1.f / (1.f + __expf((float)(3 * n) - dval));
        float hn = hstate[n * HH + o];
        hn = g * c + (1.f - g) * hn;
        hstate[n * HH + o] = hn;
        hcat_h[n * HH + o] = (f16)hn;
      }
    }
    __syncthreads();
  }

  // ---- epilogue: hid = tanh(sel @ fc1_W^T + fc1_b); out = hid @ fc2_W^T + fc2_b
  {
    float acc = 0.f;
    const int q2 = tid >> 8;  // 0..1
    const int base = q2 * 512;
    for (int i = 0; i < 512; ++i) {
      acc += hstate[base + i] * fc1T[(size_t)(base + i) * HH + o];
    }
    partials[q2 * 256 + o] = acc;
  }
  __syncthreads();
  if (tid < 256) {
    float pre = partials[o] + partials[256 + o] + fc1_b[o];
    hidb[o] = fast_tanh(pre);
  }
  __syncthreads();
  if (tid < 64) {
    float p0 = 0.f, p1 = 0.f;
    for (int ooi = tid; ooi < 256; ooi += 64) {
      float h = hidb[ooi];
      p0 += h * fc2_W[ooi];
      p1 += h * fc2_W[256 + ooi];
    }
#pragma unroll
    for (int off = 32; off; off >>= 1) {
      p0 += __shfl_down(p0, off);
      p1 += __shfl_down(p1, off);
    }
    if (tid == 0) {
      out[b * 2 + 0] = p0 + fc2_b[0];
      out[b * 2 + 1] = p1 + fc2_b[1];
    }
  }
}

// ---------------------------------------------------------------------------
// Host launcher
// ws layout: [0,512K) Wpack | [512K,768K) WiT | [768K,1792K) fc1T | [1792K,+16M) U
// ---------------------------------------------------------------------------
extern "C" void kernel_launch(void* const* d_in, const int* in_sizes, int n_in,
                              void* d_out, int out_size, void* d_ws, size_t ws_size,
                              hipStream_t stream) {
  const int* src = (const int*)d_in[0];
  const int* input_len = (const int*)d_in[1];
  const float* fix_src = (const float*)d_in[2];
  const float* emb = (const float*)d_in[3];
  const float* Wi = (const float*)d_in[4];
  const float* bi = (const float*)d_in[5];
  const float* Wh = (const float*)d_in[6];
  const float* bh = (const float*)d_in[7];
  const float* fc1_W = (const float*)d_in[8];
  const float* fc1_b = (const float*)d_in[9];
  const float* fc2_W = (const float*)d_in[10];
  const float* fc2_b = (const float*)d_in[11];
  float* out = (float*)d_out;

  char* ws = (char*)d_ws;
  uint4* Wpack = (uint4*)(ws);                 // 512 KB
  float* WiT = (float*)(ws + (512ull << 10));  // 256 KB
  float* fc1T = (float*)(ws + (768ull << 10)); // 1 MB
  f16* U = (f16*)(ws + (1792ull << 10));       // 16 MB
  const size_t needed = (1792ull << 10) + (size_t)BB * SS * HH * sizeof(f16);
  if (ws_size < needed) return;

  k_pack_wh<<<128, 256, 0, stream>>>(Wh, Wpack);
  k_transpose8<<<(65536 + 255) / 256, 256, 0, stream>>>(Wi, WiT, 256, 65536);
  k_transpose8<<<(262144 + 255) / 256, 256, 0, stream>>>(fc1_W, fc1T, 1024, 262144);
  k_precompute_u<<<BB * SS / 32, 256, 0, stream>>>(src, emb, WiT, bi, bh, U);
  k_recurrence<<<BB, TT, 0, stream>>>(Wpack, U, fix_src, input_len, fc1T, fc1_b,
                                      fc2_W, fc2_b, out);
}

// Round 3
// 1117.849 us; speedup vs baseline: 1.9438x; 1.0948x over previous
//
#include <hip/hip_runtime.h>
#include <stdint.h>

// Problem constants
constexpr int BB = 64;     // batch
constexpr int SS = 512;    // seq len
constexpr int DD = 256;    // emb dim
constexpr int HH = 256;    // hidden
constexpr int NHH = 4;     // heads
constexpr int KK = 1024;   // NH*H recurrent input dim

// Recurrence geometry: WG = 512 threads, one WG per batch element.
// Thread t: g = t&63, ch = t>>6. Covers outputs {g, g+64, g+128, g+192}
// over input chunk [128*ch, 128*ch+128) -> 64 uint4 weight slots/thread.
// Slot regions: 52 VGPR (208 regs) + 6 LDS (48 KB) + 6 streamed per step.
// 208+24+~20 working ~= 252 <= 256-reg cap of launch_bounds(512,2) --
// round-2 failed at 260 regs (compiler sank ALL weight loads into the loop).
constexpr int TT = 512;

typedef _Float16 f16;
typedef _Float16 f16x2 __attribute__((ext_vector_type(2)));

__device__ inline float dot2p(uint32_t a, uint32_t b, float c) {
  f16x2 av = __builtin_bit_cast(f16x2, a);
  f16x2 bv = __builtin_bit_cast(f16x2, b);
#if defined(__has_builtin)
#if __has_builtin(__builtin_amdgcn_fdot2)
  return __builtin_amdgcn_fdot2(av, bv, c, false);
#else
  return c + (float)av.x * (float)bv.x + (float)av.y * (float)bv.y;
#endif
#else
  return c + (float)av.x * (float)bv.x + (float)av.y * (float)bv.y;
#endif
}

__device__ inline float dot8(uint4 w, uint4 a, float c) {
  c = dot2p(w.x, a.x, c);
  c = dot2p(w.y, a.y, c);
  c = dot2p(w.z, a.z, c);
  c = dot2p(w.w, a.w, c);
  return c;
}

__device__ inline uint32_t pack2(float a, float b) {
  f16x2 v;
  v.x = (f16)a;
  v.y = (f16)b;
  return __builtin_bit_cast(uint32_t, v);
}

__device__ inline float fast_tanh(float x) {
  x = fminf(fmaxf(x, -15.f), 15.f);
  float e = __expf(2.f * x);
  return 1.f - 2.f / (e + 1.f);
}

// ---------------------------------------------------------------------------
// Prep A1: pack Wh [256,1024] fp32 -> Wpack f16 in slot layout
// Wpack[m*512 + t], t = ch*64 + g. Slot m -> (j, k):
//   m<52: j=m>>2, k=m&3 | m<56: j=13,k=m-52 | m<60: j=14,k=m-56 | else j=15,k=m-60
// holds Wh[g + 64k][128*ch + 8j .. +8) as 8 packed f16.
// ---------------------------------------------------------------------------
__global__ void k_pack_wh(const float* __restrict__ Wh, uint4* __restrict__ Wpack) {
  int gid = blockIdx.x * blockDim.x + threadIdx.x;  // 32768
  int m = gid >> 9, t = gid & 511;
  int ch = t >> 6, g = t & 63;
  int j, k;
  if (m < 52) {
    j = m >> 2;
    k = m & 3;
  } else if (m < 56) {
    j = 13;
    k = m - 52;
  } else if (m < 60) {
    j = 14;
    k = m - 56;
  } else {
    j = 15;
    k = m - 60;
  }
  int row = g + 64 * k;
  int col = 128 * ch + 8 * j;
  const float* s = Wh + row * KK + col;
  uint4 w;
  w.x = pack2(s[0], s[1]);
  w.y = pack2(s[2], s[3]);
  w.z = pack2(s[4], s[5]);
  w.w = pack2(s[6], s[7]);
  Wpack[gid] = w;
}

// ---------------------------------------------------------------------------
// Prep A2/A3: transpose src[r, C] (r in [0,256)) -> dst[c*256 + r]
// ---------------------------------------------------------------------------
__global__ void k_transpose8(const float* __restrict__ src, float* __restrict__ dst,
                             int C, int total) {
  int gid = blockIdx.x * blockDim.x + threadIdx.x;
  if (gid >= total) return;
  int r = gid & 255, c = gid >> 8;
  dst[gid] = src[r * C + c];
}

// ---------------------------------------------------------------------------
// Prep B: U[row, o] = emb[src[row]] @ Wi^T + bi + bh   (f16 out)
// Column-per-thread (thread = output col o, 32 rows), 8-d tiles.
// Each WiT element read exactly once per WG (round-2 version re-read 8x).
// ---------------------------------------------------------------------------
__global__ __launch_bounds__(256) void k_precompute_u(
    const int* __restrict__ src, const float* __restrict__ emb,
    const float* __restrict__ WiT, const float* __restrict__ bi,
    const float* __restrict__ bh, f16* __restrict__ U) {
  __shared__ float xs[32 * 256];
  __shared__ int srcs[32];
  const int tid = threadIdx.x;
  const int row0 = blockIdx.x * 32;
  if (tid < 32) srcs[tid] = src[row0 + tid];
  __syncthreads();
  for (int i = tid; i < 32 * 256; i += 256) {
    int r = i >> 8, d = i & 255;
    xs[i] = emb[srcs[r] * DD + d];
  }
  __syncthreads();
  const int o = tid;
  float acc[32];
#pragma unroll
  for (int r = 0; r < 32; ++r) acc[r] = 0.f;
  for (int d0 = 0; d0 < 256; d0 += 8) {
    float w[8];
#pragma unroll
    for (int j = 0; j < 8; ++j) w[j] = WiT[(d0 + j) * 256 + o];  // coalesced
#pragma unroll
    for (int r = 0; r < 32; ++r) {
      const float4* xp = (const float4*)(xs + r * 256 + d0);  // broadcast
      float4 x0 = xp[0], x1 = xp[1];
      acc[r] += x0.x * w[0] + x0.y * w[1] + x0.z * w[2] + x0.w * w[3] +
                x1.x * w[4] + x1.y * w[5] + x1.z * w[6] + x1.w * w[7];
    }
  }
  float bias = bi[o] + bh[o];
#pragma unroll
  for (int r = 0; r < 32; ++r)
    U[(size_t)(row0 + r) * HH + o] = (f16)(acc[r] + bias);
}

// ---------------------------------------------------------------------------
// Main recurrence: one WG (512 threads = 8 waves) per batch element.
// Wave w == chunk ch (t>>6 is wave-uniform) -> act reads are pure broadcasts.
// ---------------------------------------------------------------------------
__global__ __launch_bounds__(512, 2) void k_recurrence(
    const uint4* __restrict__ Wpack, const f16* __restrict__ U,
    const float* __restrict__ fix_src, const int* __restrict__ input_len,
    const float* __restrict__ fc1T, const float* __restrict__ fc1_b,
    const float* __restrict__ fc2_W, const float* __restrict__ fc2_b,
    float* __restrict__ out) {
  __shared__ uint4 wlds[6 * TT];      // 48 KB weights (slots 52..57)
  __shared__ uint4 hcatv[KK / 8];     // 2 KB f16 activations
  __shared__ float hstate[NHH * HH];  // 4 KB fp32 master h
  __shared__ float partials[2048];    // 8 KB
  __shared__ float hidb[HH];          // 1 KB  -> total 63 KB
  f16* hcat_h = (f16*)hcatv;

  const int b = blockIdx.x;
  const int t = threadIdx.x;
  const int o = t & 255;
  const int g = t & 63, ch = t >> 6;

  // one-time: weights into VGPRs + LDS
  uint4 wv[52];
#pragma unroll
  for (int m = 0; m < 52; ++m) wv[m] = Wpack[m * TT + t];
#pragma unroll
  for (int i = 0; i < 6; ++i) wlds[i * TT + t] = Wpack[(52 + i) * TT + t];
  hstate[t] = 0.f;
  hstate[512 + t] = 0.f;
  if (t < KK / 8) hcatv[t] = make_uint4(0u, 0u, 0u, 0u);
  __syncthreads();

  const uint4* Wstr = Wpack + 58 * TT;  // streamed slots 58..63
  const int len = input_len[b];
  const f16* Ub = U + (size_t)b * SS * HH;
  const float* fsb = fix_src + b * SS;
  const uint4* actp = hcatv + ch * 16;  // wave-uniform base

#pragma unroll 1
  for (int step = 0; step < len; ++step) {
    uint4 st0 = Wstr[t];            // issue L2 streams early; consumed last
    uint4 st1 = Wstr[TT + t];
    uint4 st2 = Wstr[2 * TT + t];
    uint4 st3 = Wstr[3 * TT + t];
    uint4 st4 = Wstr[4 * TT + t];
    uint4 st5 = Wstr[5 * TT + t];
    float uval = 0.f, dval = 0.f;
    if (t < 256) {
      uval = (float)Ub[step * HH + o];
      dval = fsb[step];
    }
    float a0 = 0.f, a1 = 0.f, a2 = 0.f, a3 = 0.f;
#pragma unroll
    for (int j = 0; j < 13; ++j) {
      uint4 a = actp[j];
      a0 = dot8(wv[4 * j + 0], a, a0);
      a1 = dot8(wv[4 * j + 1], a, a1);
      a2 = dot8(wv[4 * j + 2], a, a2);
      a3 = dot8(wv[4 * j + 3], a, a3);
    }
    {
      uint4 a = actp[13];
      a0 = dot8(wlds[0 * TT + t], a, a0);
      a1 = dot8(wlds[1 * TT + t], a, a1);
      a2 = dot8(wlds[2 * TT + t], a, a2);
      a3 = dot8(wlds[3 * TT + t], a, a3);
    }
    {
      uint4 a = actp[14];
      a0 = dot8(wlds[4 * TT + t], a, a0);
      a1 = dot8(wlds[5 * TT + t], a, a1);
      a2 = dot8(st0, a, a2);
      a3 = dot8(st1, a, a3);
    }
    {
      uint4 a = actp[15];
      a0 = dot8(st2, a, a0);
      a1 = dot8(st3, a, a1);
      a2 = dot8(st4, a, a2);
      a3 = dot8(st5, a, a3);
    }
    partials[ch * 256 + g] = a0;
    partials[ch * 256 + 64 + g] = a1;
    partials[ch * 256 + 128 + g] = a2;
    partials[ch * 256 + 192 + g] = a3;
    __syncthreads();
    if (t < 256) {
      float pre = uval;
#pragma unroll
      for (int c2 = 0; c2 < 8; ++c2) pre += partials[c2 * 256 + o];
      float c = fast_tanh(pre);
#pragma unroll
      for (int n = 0; n < NHH; ++n) {
        float gt = 1.f / (1.f + __expf((float)(3 * n) - dval));
        float hn = hstate[n * HH + o];
        hn = gt * c + (1.f - gt) * hn;
        hstate[n * HH + o] = hn;
        hcat_h[n * HH + o] = (f16)hn;
      }
    }
    __syncthreads();
  }

  // ---- epilogue: hid = tanh(sel @ fc1_W^T + fc1_b); out = hid @ fc2_W^T + fc2_b
  {
    float acc = 0.f;
    const int q2 = t >> 8;  // 0..1
    const int base = q2 * 512;
    for (int i = 0; i < 512; ++i) {
      acc += hstate[base + i] * fc1T[(size_t)(base + i) * HH + o];
    }
    partials[q2 * 256 + o] = acc;
  }
  __syncthreads();
  if (t < 256) {
    float pre = partials[o] + partials[256 + o] + fc1_b[o];
    hidb[o] = fast_tanh(pre);
  }
  __syncthreads();
  if (t < 64) {
    float p0 = 0.f, p1 = 0.f;
    for (int oi = t; oi < 256; oi += 64) {
      float h = hidb[oi];
      p0 += h * fc2_W[oi];
      p1 += h * fc2_W[256 + oi];
    }
#pragma unroll
    for (int off = 32; off; off >>= 1) {
      p0 += __shfl_down(p0, off);
      p1 += __shfl_down(p1, off);
    }
    if (t == 0) {
      out[b * 2 + 0] = p0 + fc2_b[0];
      out[b * 2 + 1] = p1 + fc2_b[1];
    }
  }
}

// ---------------------------------------------------------------------------
// Host launcher
// ws layout: [0,512K) Wpack | [512K,768K) WiT | [768K,1792K) fc1T | [1792K,+16M) U
// ---------------------------------------------------------------------------
extern "C" void kernel_launch(void* const* d_in, const int* in_sizes, int n_in,
                              void* d_out, int out_size, void* d_ws, size_t ws_size,
                              hipStream_t stream) {
  const int* src = (const int*)d_in[0];
  const int* input_len = (const int*)d_in[1];
  const float* fix_src = (const float*)d_in[2];
  const float* emb = (const float*)d_in[3];
  const float* Wi = (const float*)d_in[4];
  const float* bi = (const float*)d_in[5];
  const float* Wh = (const float*)d_in[6];
  const float* bh = (const float*)d_in[7];
  const float* fc1_W = (const float*)d_in[8];
  const float* fc1_b = (const float*)d_in[9];
  const float* fc2_W = (const float*)d_in[10];
  const float* fc2_b = (const float*)d_in[11];
  float* out = (float*)d_out;

  char* ws = (char*)d_ws;
  uint4* Wpack = (uint4*)(ws);                 // 512 KB
  float* WiT = (float*)(ws + (512ull << 10));  // 256 KB
  float* fc1T = (float*)(ws + (768ull << 10)); // 1 MB
  f16* U = (f16*)(ws + (1792ull << 10));       // 16 MB
  const size_t needed = (1792ull << 10) + (size_t)BB * SS * HH * sizeof(f16);
  if (ws_size < needed) return;

  k_pack_wh<<<128, 256, 0, stream>>>(Wh, Wpack);
  k_transpose8<<<(65536 + 255) / 256, 256, 0, stream>>>(Wi, WiT, 256, 65536);
  k_transpose8<<<(262144 + 255) / 256, 256, 0, stream>>>(fc1_W, fc1T, 1024, 262144);
  k_precompute_u<<<BB * SS / 32, 256, 0, stream>>>(src, emb, WiT, bi, bh, U);
  k_recurrence<<<BB, TT, 0, stream>>>(Wpack, U, fix_src, input_len, fc1T, fc1_b,
                                      fc2_W, fc2_b, out);
}